// Round 2
// baseline (116.953 us; speedup 1.0000x reference)
//
#include <hip/hip_runtime.h>
#include <hip/hip_bf16.h>

#define NN 8192

typedef float f32x4 __attribute__((ext_vector_type(4)));

// Phase 1: split-K GEMV partials.  partial[s][j] = sum_{i in split s} g_i * w[i][j]
// Grid: x = column tile (1024 cols), y = row split s.  RPS = rows per split (compile-time).
template <int RPS>
__global__ __launch_bounds__(256) void lif_gemv_part(
    const float* __restrict__ g, const float* __restrict__ w,
    float* __restrict__ partial)
{
    const int col = blockIdx.x * 1024 + threadIdx.x * 4;
    const int s   = blockIdx.y;
    const int r0  = s * RPS;

    const float* wp = w + (size_t)r0 * NN + col;
    const float* gp = g + r0;

    f32x4 acc = {0.f, 0.f, 0.f, 0.f};
    #pragma unroll
    for (int i = 0; i < RPS; ++i) {
        const float gi = gp[i];   // wave-uniform -> scalar load, cache hit
        const f32x4 wv = __builtin_nontemporal_load(
            reinterpret_cast<const f32x4*>(wp + (size_t)i * NN));
        acc.x = fmaf(gi, wv.x, acc.x);
        acc.y = fmaf(gi, wv.y, acc.y);
        acc.z = fmaf(gi, wv.z, acc.z);
        acc.w = fmaf(gi, wv.w, acc.w);
    }
    *reinterpret_cast<f32x4*>(partial + (size_t)s * NN + col) = acc;
}

// Runtime fallback (any rps) — only used if ws_size is unexpectedly small.
__global__ __launch_bounds__(256) void lif_gemv_part_rt(
    const float* __restrict__ g, const float* __restrict__ w,
    float* __restrict__ partial, int rps)
{
    const int col = blockIdx.x * 1024 + threadIdx.x * 4;
    const int s   = blockIdx.y;
    const int r0  = s * rps;

    const float* wp = w + (size_t)r0 * NN + col;
    const float* gp = g + r0;

    f32x4 acc = {0.f, 0.f, 0.f, 0.f};
    #pragma unroll 8
    for (int i = 0; i < rps; ++i) {
        const float gi = gp[i];
        const f32x4 wv = __builtin_nontemporal_load(
            reinterpret_cast<const f32x4*>(wp + (size_t)i * NN));
        acc.x = fmaf(gi, wv.x, acc.x);
        acc.y = fmaf(gi, wv.y, acc.y);
        acc.z = fmaf(gi, wv.z, acc.z);
        acc.w = fmaf(gi, wv.w, acc.w);
    }
    *reinterpret_cast<f32x4*>(partial + (size_t)s * NN + col) = acc;
}

// Phase 2: deterministic sequential reduction over splits + LIF pointwise.
__global__ __launch_bounds__(256) void lif_pointwise(
    const float* __restrict__ partial, int nsplits,
    const float* __restrict__ x_in, const float* __restrict__ v,
    const float* __restrict__ E_L, const float* __restrict__ tau_m,
    float* __restrict__ out)
{
    const int j = blockIdx.x * blockDim.x + threadIdx.x;
    if (j >= NN) return;

    float I = 0.f;
    for (int s = 0; s < nsplits; ++s)          // fixed order: deterministic
        I += partial[(size_t)s * NN + j];

    const float arg  = 12.0f * I / 8192.0f;
    const float Isig = 1.0f / (1.0f + expf(-arg));
    const float Ifull = Isig + 0.9f * x_in[j];

    const float el  = E_L[j];
    const float vv  = v[j];
    const float v_next = vv + (el - vv + Ifull * (30.0f - el)) / tau_m[j];

    out[j] = 1.0f / (1.0f + expf(30.0f - v_next));
}

extern "C" void kernel_launch(void* const* d_in, const int* in_sizes, int n_in,
                              void* d_out, int out_size, void* d_ws, size_t ws_size,
                              hipStream_t stream) {
    const float* x_in  = (const float*)d_in[0];
    const float* v     = (const float*)d_in[1];
    const float* g     = (const float*)d_in[2];
    const float* w     = (const float*)d_in[3];
    const float* E_L   = (const float*)d_in[4];
    const float* tau_m = (const float*)d_in[5];
    // d_in[6] = tau_g, unused by the reference
    float* out     = (float*)d_out;
    float* partial = (float*)d_ws;

    // Largest power-of-2 split count that fits the workspace, capped at 256.
    int S = 256;
    while (S > 1 && (size_t)S * NN * sizeof(float) > ws_size) S >>= 1;

    dim3 grid1(NN / 1024, S);
    switch (S) {
        case 256: lif_gemv_part<32 ><<<grid1, 256, 0, stream>>>(g, w, partial); break;
        case 128: lif_gemv_part<64 ><<<grid1, 256, 0, stream>>>(g, w, partial); break;
        case  64: lif_gemv_part<128><<<grid1, 256, 0, stream>>>(g, w, partial); break;
        default:  lif_gemv_part_rt <<<grid1, 256, 0, stream>>>(g, w, partial, NN / S); break;
    }
    lif_pointwise<<<NN / 256, 256, 0, stream>>>(partial, S, x_in, v, E_L, tau_m, out);
}

// Round 3
// 50.005 us; speedup vs baseline: 2.3388x; 2.3388x over previous
//
#include <hip/hip_runtime.h>
#include <hip/hip_bf16.h>

#define NN 8192

typedef float f32x4 __attribute__((ext_vector_type(4)));

// Phase 1: split-K GEMV partials. partial[s][j] = sum_{i in split s} g_i * w[i][j]
// EXACT R1 structure (proven 78.9us): runtime rps, unroll 8, plain loads.
__global__ __launch_bounds__(256) void lif_gemv_part(
    const float* __restrict__ g, const float* __restrict__ w,
    float* __restrict__ partial, int rows_per_split)
{
    const int col = blockIdx.x * 1024 + threadIdx.x * 4;
    const int s   = blockIdx.y;
    const int r0  = s * rows_per_split;

    const float* wp = w + (size_t)r0 * NN + col;
    const float* gp = g + r0;

    f32x4 acc = {0.f, 0.f, 0.f, 0.f};
    #pragma unroll 8
    for (int i = 0; i < rows_per_split; ++i) {
        const float gi = gp[i];                       // wave-uniform scalar load
        const f32x4 wv = *reinterpret_cast<const f32x4*>(wp + (size_t)i * NN);
        acc.x = fmaf(gi, wv.x, acc.x);
        acc.y = fmaf(gi, wv.y, acc.y);
        acc.z = fmaf(gi, wv.z, acc.z);
        acc.w = fmaf(gi, wv.w, acc.w);
    }
    *reinterpret_cast<f32x4*>(partial + (size_t)s * NN + col) = acc;
}

__device__ __forceinline__ float lif_activation(
    float I, float x, float vv, float el, float tm)
{
    const float arg   = 12.0f * I / 8192.0f;
    const float Isig  = 1.0f / (1.0f + expf(-arg));
    const float Ifull = Isig + 0.9f * x;
    const float v_next = vv + (el - vv + Ifull * (30.0f - el)) / tm;
    return 1.0f / (1.0f + expf(30.0f - v_next));
}

// Phase 2: parallel deterministic reduction + LIF pointwise.
// 256 blocks x 256 threads; block owns 32 columns; 8 split-groups per column.
template <int S>
__global__ __launch_bounds__(256) void lif_pointwise_t(
    const float* __restrict__ partial,
    const float* __restrict__ x_in, const float* __restrict__ v,
    const float* __restrict__ E_L, const float* __restrict__ tau_m,
    float* __restrict__ out)
{
    const int cl = threadIdx.x & 31;   // column within block
    const int kg = threadIdx.x >> 5;   // split group 0..7
    const int j  = blockIdx.x * 32 + cl;
    constexpr int PER = S / 8;

    float acc = 0.f;
    #pragma unroll
    for (int s = 0; s < PER; ++s)      // fixed order: deterministic
        acc += partial[(size_t)(kg * PER + s) * NN + j];

    __shared__ float red[8][32];
    red[kg][cl] = acc;
    __syncthreads();

    if (threadIdx.x < 32) {
        float I = red[0][cl];
        #pragma unroll
        for (int k = 1; k < 8; ++k) I += red[k][cl];   // fixed order
        out[j] = lif_activation(I, x_in[j], v[j], E_L[j], tau_m[j]);
    }
}

// Runtime fallback (any nsplits) — simple sequential version.
__global__ __launch_bounds__(256) void lif_pointwise_rt(
    const float* __restrict__ partial, int nsplits,
    const float* __restrict__ x_in, const float* __restrict__ v,
    const float* __restrict__ E_L, const float* __restrict__ tau_m,
    float* __restrict__ out)
{
    const int j = blockIdx.x * blockDim.x + threadIdx.x;
    if (j >= NN) return;
    float I = 0.f;
    for (int s = 0; s < nsplits; ++s)
        I += partial[(size_t)s * NN + j];
    out[j] = lif_activation(I, x_in[j], v[j], E_L[j], tau_m[j]);
}

extern "C" void kernel_launch(void* const* d_in, const int* in_sizes, int n_in,
                              void* d_out, int out_size, void* d_ws, size_t ws_size,
                              hipStream_t stream) {
    const float* x_in  = (const float*)d_in[0];
    const float* v     = (const float*)d_in[1];
    const float* g     = (const float*)d_in[2];
    const float* w     = (const float*)d_in[3];
    const float* E_L   = (const float*)d_in[4];
    const float* tau_m = (const float*)d_in[5];
    // d_in[6] = tau_g, unused by the reference
    float* out     = (float*)d_out;
    float* partial = (float*)d_ws;

    // Largest power-of-2 split count that fits the workspace, capped at 128 (R1-proven).
    int S = 128;
    while (S > 1 && (size_t)S * NN * sizeof(float) > ws_size) S >>= 1;

    dim3 grid1(NN / 1024, S);
    lif_gemv_part<<<grid1, 256, 0, stream>>>(g, w, partial, NN / S);

    switch (S) {
        case 128: lif_pointwise_t<128><<<NN / 32, 256, 0, stream>>>(partial, x_in, v, E_L, tau_m, out); break;
        case  64: lif_pointwise_t< 64><<<NN / 32, 256, 0, stream>>>(partial, x_in, v, E_L, tau_m, out); break;
        case  32: lif_pointwise_t< 32><<<NN / 32, 256, 0, stream>>>(partial, x_in, v, E_L, tau_m, out); break;
        default:  lif_pointwise_rt<<<NN / 256, 256, 0, stream>>>(partial, S, x_in, v, E_L, tau_m, out); break;
    }
}